// Round 7
// baseline (623.144 us; speedup 1.0000x reference)
//
#include <hip/hip_runtime.h>
#include <hip/hip_bf16.h>
#include <stdint.h>

typedef __attribute__((ext_vector_type(8))) short bf16x8;
typedef __attribute__((ext_vector_type(4))) float f32x4;
typedef __attribute__((ext_vector_type(8))) unsigned short u16x8;

#define BM 256
#define BN 256
#define BKT 64
#define ABYTES (BM * BKT * 2)        // 32768
#define BBYTES (BN * BKT * 2)        // 32768
#define BUFBYTES (ABYTES + BBYTES)   // 65536; 2 buffers = 128 KB LDS

// ---- MXFP8 quant-dequant to bf16 (verified r1/r5/r6: absmax 0.03125) -------
__device__ __forceinline__ float mx_qd_elem(float x, int e) {
    float xs = ldexpf(x, -e);
    xs = fminf(448.f, fmaxf(-448.f, xs));
    float a = fabsf(xs);
    float r;
    if (a < 0.015625f) {                  // below 2^-6: e4m3 subnormal, quantum 2^-9
        r = ldexpf(rintf(ldexpf(a, 9)), -9);
    } else {                              // normal: quantum 2^(E-3)
        int E = (int)((__float_as_uint(a) >> 23) & 0xFF) - 127;
        r = ldexpf(rintf(ldexpf(a, 3 - E)), E - 3);
    }
    r = copysignf(r, xs);
    return ldexpf(r, e);
}

__global__ __launch_bounds__(256) void mx_quant_bf16(
    const float* __restrict__ in, uint16_t* __restrict__ out, int nblk) {
    int t = blockIdx.x * 256 + threadIdx.x;
    if (t >= nblk) return;
    const float4* p = (const float4*)(in + (size_t)t * 32);
    float v[32];
#pragma unroll
    for (int i = 0; i < 8; ++i) {
        float4 fv = p[i];
        v[4 * i + 0] = fv.x; v[4 * i + 1] = fv.y;
        v[4 * i + 2] = fv.z; v[4 * i + 3] = fv.w;
    }
    float amax = 0.f;
#pragma unroll
    for (int i = 0; i < 32; ++i) amax = fmaxf(amax, fabsf(v[i]));
    amax = fmaxf(amax, 1.17549435e-38f);
    int e = (int)((__float_as_uint(amax) >> 23) & 0xFF) - 127 - 8;

    unsigned short res[32];
#pragma unroll
    for (int i = 0; i < 32; ++i) {
        float d = mx_qd_elem(v[i], e);
        res[i] = (unsigned short)(__float_as_uint(d) >> 16);
    }
    u16x8* o = (u16x8*)(out + (size_t)t * 32);
#pragma unroll
    for (int j = 0; j < 4; ++j) {
        u16x8 pack;
#pragma unroll
        for (int i = 0; i < 8; ++i) pack[i] = res[8 * j + i];
        o[j] = pack;
    }
}

// ---- 256x256 8-phase bf16 GEMM (m201 structure): C = A * B^T + bias --------
// 8 waves (2M x 4N), per-wave 128x64 (acc[8][4]); BK=64; 2-buf LDS;
// per K-tile: 4 phases (quadrants), 2 barriers each, counted vmcnt(4)/(2);
// stage order per tile: [B4 B5 B6 B7 A0 A2 A1 A3] (64-row rounds).
#define GLOAD(srcp, ldsoff)                                                     \
    __builtin_amdgcn_global_load_lds(                                           \
        (const __attribute__((address_space(1))) void*)(srcp),                  \
        (__attribute__((address_space(3))) void*)&lds[ldsoff], 16, 0, 0)

__global__ __launch_bounds__(512, 2) void gemm_8p_bf16(
    const uint16_t* __restrict__ A, const uint16_t* __restrict__ B,
    const float* __restrict__ bias, float* __restrict__ C,
    int Nrows, int K, int O) {
    __shared__ __align__(16) uint8_t lds[2 * BUFBYTES];   // 128 KB

    const int tid  = threadIdx.x;
    const int lane = tid & 63;
    const int w    = tid >> 6;
    const int f    = lane & 15, g = lane >> 4;
    const int wm   = w >> 2,    wn = w & 3;     // 2M x 4N

    // T1: bijective XCD swizzle (nwg = 1024, %8 == 0)
    const int nwg  = gridDim.x * gridDim.y;
    const int flat = blockIdx.y * gridDim.x + blockIdx.x;
    const int swz  = (flat & 7) * (nwg >> 3) + (flat >> 3);
    const int bx   = swz % gridDim.x, by = swz / gridDim.x;
    const int rowBase = by * BM, colBase = bx * BN;

    // staging precompute: round = 64 rows x 128 B; thread covers 16 B.
    // linear LDS dest (rule 21); SOURCE col pre-inverse-swizzled (r5/r6-verified).
    const int sri = tid >> 3;                                // row in round
    const int ssc = ((tid & 7) * 16) ^ ((sri & 7) << 4);
    const int sld = tid * 16;                                // LDS off in round
    const size_t K2 = (size_t)K * 2;
    const uint8_t* gAr[4]; const uint8_t* gBr[4];
#pragma unroll
    for (int r = 0; r < 4; ++r) {
        gAr[r] = (const uint8_t*)A + (size_t)(rowBase + r * 64 + sri) * K2 + ssc;
        gBr[r] = (const uint8_t*)B + (size_t)(colBase + r * 64 + sri) * K2 + ssc;
    }
#define SA(t, r) GLOAD(gAr[r] + (size_t)(t) * (BKT * 2),                        \
                       (((t) & 1) * BUFBYTES) + (r) * 8192 + sld)
#define SB(t, r) GLOAD(gBr[r] + (size_t)(t) * (BKT * 2),                        \
                       (((t) & 1) * BUFBYTES) + ABYTES + (r) * 8192 + sld)

    // swizzled frag-read offsets (relative to buf base; r6-verified, 0 conflicts)
    int aoff[8][2], boff[4][2];
#pragma unroll
    for (int kk = 0; kk < 2; ++kk) {
        const int colb = (kk * 64 + g * 16) ^ ((f & 7) << 4);
#pragma unroll
        for (int m = 0; m < 8; ++m)
            aoff[m][kk] = (wm * 128 + m * 16 + f) * 128 + colb;
#pragma unroll
        for (int n = 0; n < 4; ++n)
            boff[n][kk] = ABYTES + (wn * 64 + n * 16 + f) * 128 + colb;
    }

    f32x4 acc[8][4];
#pragma unroll
    for (int m = 0; m < 8; ++m)
#pragma unroll
        for (int n = 0; n < 4; ++n)
#pragma unroll
            for (int j = 0; j < 4; ++j) acc[m][n][j] = 0.f;

    const int nt = K / BKT;   // 64

#define LD_A(AF, MB) do {                                                       \
        _Pragma("unroll") for (int _m = 0; _m < 4; ++_m) {                      \
            AF[_m][0] = *(const bf16x8*)&lds[bb + aoff[(MB) + _m][0]];          \
            AF[_m][1] = *(const bf16x8*)&lds[bb + aoff[(MB) + _m][1]];          \
        } } while (0)
#define LD_B(BF, NB) do {                                                       \
        _Pragma("unroll") for (int _n = 0; _n < 2; ++_n) {                      \
            BF[_n][0] = *(const bf16x8*)&lds[bb + boff[(NB) + _n][0]];          \
            BF[_n][1] = *(const bf16x8*)&lds[bb + boff[(NB) + _n][1]];          \
        } } while (0)
#define MFMA_Q(MB, NB, AF, BF) do {                                             \
        __builtin_amdgcn_s_setprio(1);                                          \
        _Pragma("unroll") for (int _m = 0; _m < 4; ++_m)                        \
        _Pragma("unroll") for (int _n = 0; _n < 2; ++_n) {                      \
            acc[(MB)+_m][(NB)+_n] = __builtin_amdgcn_mfma_f32_16x16x32_bf16(    \
                AF[_m][0], BF[_n][0], acc[(MB)+_m][(NB)+_n], 0, 0, 0);          \
            acc[(MB)+_m][(NB)+_n] = __builtin_amdgcn_mfma_f32_16x16x32_bf16(    \
                AF[_m][1], BF[_n][1], acc[(MB)+_m][(NB)+_n], 0, 0, 0);          \
        }                                                                       \
        __builtin_amdgcn_s_setprio(0);                                          \
    } while (0)
#define BAR()    __builtin_amdgcn_s_barrier()
#define LGKM0()  do { asm volatile("s_waitcnt lgkmcnt(0)" ::: "memory");        \
                      __builtin_amdgcn_sched_barrier(0); } while (0)

    // prologue: stage tile 0 in ledger order; leave A1,A3 in flight (vmcnt(2))
    SB(0, 0); SB(0, 1); SB(0, 2); SB(0, 3);
    SA(0, 0); SA(0, 2); SA(0, 1); SA(0, 3);
    asm volatile("s_waitcnt vmcnt(2)" ::: "memory");
    __builtin_amdgcn_sched_barrier(0);
    BAR();

    for (int t = 0; t < nt; ++t) {
        const int bb = (t & 1) * BUFBYTES;
        const bool pf = (t + 1) < nt;
        bf16x8 afr[4][2], bfr[2][2], bfr2[2][2];

        // ---- phase 0: quadrant (mh0, nh0) — 12 ds_reads, stage B4',B5'
        LD_A(afr, 0);
        LD_B(bfr, 0);
        if (pf) { SB(t + 1, 0); SB(t + 1, 1); }
        asm volatile("s_waitcnt lgkmcnt(8)" ::: "memory");   // throttle 12 reads
        BAR(); LGKM0();
        MFMA_Q(0, 0, afr, bfr);
        BAR();

        // ---- phase 1: quadrant (mh0, nh1) — 4 ds_reads, stage B6',B7'
        LD_B(bfr2, 2);
        if (pf) { SB(t + 1, 2); SB(t + 1, 3); }
        BAR(); LGKM0();
        MFMA_Q(0, 2, afr, bfr2);
        // retire prior tile's A1,A3 before phase 2 reads them (counted, not 0)
        if (pf) asm volatile("s_waitcnt vmcnt(4)" ::: "memory");
        else    asm volatile("s_waitcnt vmcnt(0)" ::: "memory");
        __builtin_amdgcn_sched_barrier(0);
        BAR();

        // ---- phase 2: quadrant (mh1, nh1) — 8 ds_reads, stage A0',A2'
        LD_A(afr, 4);
        if (pf) { SA(t + 1, 0); SA(t + 1, 2); }
        BAR(); LGKM0();
        MFMA_Q(4, 2, afr, bfr2);
        BAR();

        // ---- phase 3: quadrant (mh1, nh0) — 4 ds_reads, stage A1',A3'
        LD_B(bfr, 0);
        if (pf) { SA(t + 1, 1); SA(t + 1, 3); }
        BAR(); LGKM0();
        MFMA_Q(4, 0, afr, bfr);
        // retire next tile's B4..B7,A0,A2 (leave A1',A3' flying)
        if (pf) asm volatile("s_waitcnt vmcnt(2)" ::: "memory");
        else    asm volatile("s_waitcnt vmcnt(0)" ::: "memory");
        __builtin_amdgcn_sched_barrier(0);
        BAR();
    }
#undef SA
#undef SB
#undef LD_A
#undef LD_B
#undef MFMA_Q
#undef BAR
#undef LGKM0

    // epilogue: C/D layout col=lane&15, row=(lane>>4)*4+j (r1/r5/r6-verified)
    const int qr = g * 4;
#pragma unroll
    for (int n = 0; n < 4; ++n) {
        int col = colBase + wn * 64 + n * 16 + f;
        float bv = bias[col];
#pragma unroll
        for (int m = 0; m < 8; ++m) {
            int r0 = rowBase + wm * 128 + m * 16 + qr;
#pragma unroll
            for (int j = 0; j < 4; ++j)
                C[(size_t)(r0 + j) * O + col] = acc[m][n][j] + bv;
        }
    }
}

extern "C" void kernel_launch(void* const* d_in, const int* in_sizes, int n_in,
                              void* d_out, int out_size, void* d_ws, size_t ws_size,
                              hipStream_t stream) {
    const float* x    = (const float*)d_in[0];
    const float* wgt  = (const float*)d_in[1];
    const float* bias = (const float*)d_in[2];
    float* out = (float*)d_out;

    const int D_OUT = in_sizes[2];             // 4096
    const int D_IN  = in_sizes[1] / D_OUT;     // 4096
    const int NROWS = in_sizes[0] / D_IN;      // 16384

    uint16_t* xq = (uint16_t*)d_ws;                     // 128 MB
    uint16_t* wq = xq + (size_t)NROWS * D_IN;           //  32 MB

    int nblkx = NROWS * (D_IN / 32);
    int nblkw = D_OUT * (D_IN / 32);
    mx_quant_bf16<<<dim3((nblkx + 255) / 256), dim3(256), 0, stream>>>(x, xq, nblkx);
    mx_quant_bf16<<<dim3((nblkw + 255) / 256), dim3(256), 0, stream>>>(wgt, wq, nblkw);

    dim3 grid(D_OUT / BN, NROWS / BM);   // (16, 64) = 1024 blocks
    gemm_8p_bf16<<<grid, dim3(512), 0, stream>>>(xq, wq, bias, out,
                                                 NROWS, D_IN, D_OUT);
}

// Round 8
// 587.336 us; speedup vs baseline: 1.0610x; 1.0610x over previous
//
#include <hip/hip_runtime.h>
#include <hip/hip_bf16.h>
#include <stdint.h>

typedef __attribute__((ext_vector_type(8))) short bf16x8;
typedef __attribute__((ext_vector_type(4))) float f32x4;
typedef __attribute__((ext_vector_type(8))) unsigned short u16x8;

#define BM 256
#define BN 256
#define BKT 64
#define ABYTES (BM * BKT * 2)        // 32768
#define BBYTES (BN * BKT * 2)        // 32768
#define BUFBYTES (ABYTES + BBYTES)   // 65536; 2 buffers = 128 KB LDS

// ---- MXFP8 quant-dequant to bf16 (verified r1/r5/r6/r7: absmax 0.03125) ----
__device__ __forceinline__ float mx_qd_elem(float x, int e) {
    float xs = ldexpf(x, -e);
    xs = fminf(448.f, fmaxf(-448.f, xs));
    float a = fabsf(xs);
    float r;
    if (a < 0.015625f) {                  // below 2^-6: e4m3 subnormal, quantum 2^-9
        r = ldexpf(rintf(ldexpf(a, 9)), -9);
    } else {                              // normal: quantum 2^(E-3)
        int E = (int)((__float_as_uint(a) >> 23) & 0xFF) - 127;
        r = ldexpf(rintf(ldexpf(a, 3 - E)), E - 3);
    }
    r = copysignf(r, xs);
    return ldexpf(r, e);
}

__global__ __launch_bounds__(256) void mx_quant_bf16(
    const float* __restrict__ in, uint16_t* __restrict__ out, int nblk) {
    int t = blockIdx.x * 256 + threadIdx.x;
    if (t >= nblk) return;
    const float4* p = (const float4*)(in + (size_t)t * 32);
    float v[32];
#pragma unroll
    for (int i = 0; i < 8; ++i) {
        float4 fv = p[i];
        v[4 * i + 0] = fv.x; v[4 * i + 1] = fv.y;
        v[4 * i + 2] = fv.z; v[4 * i + 3] = fv.w;
    }
    float amax = 0.f;
#pragma unroll
    for (int i = 0; i < 32; ++i) amax = fmaxf(amax, fabsf(v[i]));
    amax = fmaxf(amax, 1.17549435e-38f);
    int e = (int)((__float_as_uint(amax) >> 23) & 0xFF) - 127 - 8;

    unsigned short res[32];
#pragma unroll
    for (int i = 0; i < 32; ++i) {
        float d = mx_qd_elem(v[i], e);
        res[i] = (unsigned short)(__float_as_uint(d) >> 16);
    }
    u16x8* o = (u16x8*)(out + (size_t)t * 32);
#pragma unroll
    for (int j = 0; j < 4; ++j) {
        u16x8 pack;
#pragma unroll
        for (int i = 0; i < 8; ++i) pack[i] = res[8 * j + i];
        o[j] = pack;
    }
}

// ---- 256x256 chunk-pipelined bf16 GEMM: C = A * B^T + bias -----------------
// 8 waves (2M x 4N), per-wave 128x64 (acc[8][4]); BK=64; 2-buf LDS (128 KB);
// per K-tile: 4 read-chunks / 4 MFMA-clusters with COUNTED lgkm waits so each
// chunk's DS drain hides under the previous cluster's MFMA; 1 barrier/K-tile;
// T1 XCD swizzle; T2 XOR-swizzle (0 conflicts, r5-r7 verified); T5 setprio.
#define GLOAD(srcp, ldsoff)                                                     \
    __builtin_amdgcn_global_load_lds(                                           \
        (const __attribute__((address_space(1))) void*)(srcp),                  \
        (__attribute__((address_space(3))) void*)&lds[ldsoff], 16, 0, 0)

__global__ __launch_bounds__(512, 2) void gemm_ck_bf16(
    const uint16_t* __restrict__ A, const uint16_t* __restrict__ B,
    const float* __restrict__ bias, float* __restrict__ C,
    int Nrows, int K, int O) {
    __shared__ __align__(16) uint8_t lds[2 * BUFBYTES];   // 128 KB

    const int tid  = threadIdx.x;
    const int lane = tid & 63;
    const int w    = tid >> 6;
    const int f    = lane & 15, g = lane >> 4;
    const int wm   = w >> 2,    wn = w & 3;     // 2M x 4N

    // T1: bijective XCD swizzle (nwg = 1024, %8 == 0)
    const int nwg  = gridDim.x * gridDim.y;
    const int flat = blockIdx.y * gridDim.x + blockIdx.x;
    const int swz  = (flat & 7) * (nwg >> 3) + (flat >> 3);
    const int bx   = swz % gridDim.x, by = swz / gridDim.x;
    const int rowBase = by * BM, colBase = bx * BN;

    // staging: round = 64 rows x 128 B; thread covers 16 B. linear LDS dest
    // (rule 21); SOURCE col pre-inverse-swizzled (r5/r6-verified formulas).
    const int sri = tid >> 3;
    const int ssc = ((tid & 7) * 16) ^ ((sri & 7) << 4);
    const int sld = tid * 16;
    const size_t K2 = (size_t)K * 2;
    const uint8_t* gAr[4]; const uint8_t* gBr[4];
#pragma unroll
    for (int r = 0; r < 4; ++r) {
        gAr[r] = (const uint8_t*)A + (size_t)(rowBase + r * 64 + sri) * K2 + ssc;
        gBr[r] = (const uint8_t*)B + (size_t)(colBase + r * 64 + sri) * K2 + ssc;
    }
#define STAGE(t) do {                                                           \
        const int _buf = ((t) & 1) * BUFBYTES;                                  \
        const size_t _kb = (size_t)(t) * (BKT * 2);                             \
        _Pragma("unroll")                                                       \
        for (int _i = 0; _i < 4; ++_i)                                          \
            GLOAD(gAr[_i] + _kb, _buf + _i * 8192 + sld);                       \
        _Pragma("unroll")                                                       \
        for (int _i = 0; _i < 4; ++_i)                                          \
            GLOAD(gBr[_i] + _kb, _buf + ABYTES + _i * 8192 + sld);              \
    } while (0)

    // swizzled frag-read offsets: LDS[r][c] = G[r][c ^ ((r&7)<<4)]
    int aoff[8][2], boff[4][2];
#pragma unroll
    for (int kk = 0; kk < 2; ++kk) {
        const int colb = (kk * 64 + g * 16) ^ ((f & 7) << 4);
#pragma unroll
        for (int m = 0; m < 8; ++m)
            aoff[m][kk] = (wm * 128 + m * 16 + f) * 128 + colb;
#pragma unroll
        for (int n = 0; n < 4; ++n)
            boff[n][kk] = ABYTES + (wn * 64 + n * 16 + f) * 128 + colb;
    }

    f32x4 acc[8][4];
#pragma unroll
    for (int m = 0; m < 8; ++m)
#pragma unroll
        for (int n = 0; n < 4; ++n)
#pragma unroll
            for (int j = 0; j < 4; ++j) acc[m][n][j] = 0.f;

    const int nt = K / BKT;   // 64

#define WAITL(N) do {                                                           \
        asm volatile("s_waitcnt lgkmcnt(" #N ")" ::: "memory");                 \
        __builtin_amdgcn_sched_barrier(0);                                      \
    } while (0)
#define MFMA_C(MB, AF, BF) do {                                                 \
        __builtin_amdgcn_s_setprio(1);                                          \
        _Pragma("unroll") for (int _m = 0; _m < 4; ++_m)                        \
        _Pragma("unroll") for (int _n = 0; _n < 4; ++_n)                        \
            acc[(MB) + _m][_n] = __builtin_amdgcn_mfma_f32_16x16x32_bf16(       \
                AF[_m], BF[_n], acc[(MB) + _m][_n], 0, 0, 0);                   \
        __builtin_amdgcn_s_setprio(0);                                          \
    } while (0)

    // prologue: stage tile 0, drain, publish
    STAGE(0);
    asm volatile("s_waitcnt vmcnt(0)" ::: "memory");
    __builtin_amdgcn_sched_barrier(0);
    __builtin_amdgcn_s_barrier();
    __builtin_amdgcn_sched_barrier(0);

    for (int t = 0; t < nt; ++t) {
        const int bb = (t & 1) * BUFBYTES;
        const bool pf = (t + 1) < nt;
        bf16x8 bA[4], bB[4], aLo[4], aHi[4], aLo1[4], aHi1[4];

        // c0 (8 reads): B kk0 + A m0-3 kk0
#pragma unroll
        for (int n = 0; n < 4; ++n) bA[n] = *(const bf16x8*)&lds[bb + boff[n][0]];
#pragma unroll
        for (int m = 0; m < 4; ++m) aLo[m] = *(const bf16x8*)&lds[bb + aoff[m][0]];
        // c1 (4 reads): A m4-7 kk0
#pragma unroll
        for (int m = 0; m < 4; ++m) aHi[m] = *(const bf16x8*)&lds[bb + aoff[4 + m][0]];
        if (pf) STAGE(t + 1);            // gload issue overlaps c0 drain
        WAITL(4);                        // c0 done (c1's 4 outstanding)
        MFMA_C(0, aLo, bA);              // cluster 1; c1 drains under it
        // c2 (8 reads): B kk1 + A m0-3 kk1
#pragma unroll
        for (int n = 0; n < 4; ++n) bB[n] = *(const bf16x8*)&lds[bb + boff[n][1]];
#pragma unroll
        for (int m = 0; m < 4; ++m) aLo1[m] = *(const bf16x8*)&lds[bb + aoff[m][1]];
        WAITL(8);                        // c1 done (c2's 8 outstanding)
        MFMA_C(4, aHi, bA);              // cluster 2; c2 drains under it
        // c3 (4 reads): A m4-7 kk1
#pragma unroll
        for (int m = 0; m < 4; ++m) aHi1[m] = *(const bf16x8*)&lds[bb + aoff[4 + m][1]];
        WAITL(4);                        // c2 done (c3's 4 outstanding)
        MFMA_C(0, aLo1, bB);             // cluster 3; c3 drains under it
        WAITL(0);                        // c3 done
        MFMA_C(4, aHi1, bB);             // cluster 4
        // publish tile t+1 (issued ~3000 cyc ago) and release buffers
        asm volatile("s_waitcnt vmcnt(0)" ::: "memory");
        __builtin_amdgcn_sched_barrier(0);
        __builtin_amdgcn_s_barrier();
        __builtin_amdgcn_sched_barrier(0);
    }
#undef STAGE
#undef WAITL
#undef MFMA_C

    // epilogue: C/D layout col=lane&15, row=(lane>>4)*4+j (r1/r5/r6-verified)
    const int qr = g * 4;
#pragma unroll
    for (int n = 0; n < 4; ++n) {
        int col = colBase + wn * 64 + n * 16 + f;
        float bv = bias[col];
#pragma unroll
        for (int m = 0; m < 8; ++m) {
            int r0 = rowBase + wm * 128 + m * 16 + qr;
#pragma unroll
            for (int j = 0; j < 4; ++j)
                C[(size_t)(r0 + j) * O + col] = acc[m][n][j] + bv;
        }
    }
}

extern "C" void kernel_launch(void* const* d_in, const int* in_sizes, int n_in,
                              void* d_out, int out_size, void* d_ws, size_t ws_size,
                              hipStream_t stream) {
    const float* x    = (const float*)d_in[0];
    const float* wgt  = (const float*)d_in[1];
    const float* bias = (const float*)d_in[2];
    float* out = (float*)d_out;

    const int D_OUT = in_sizes[2];             // 4096
    const int D_IN  = in_sizes[1] / D_OUT;     // 4096
    const int NROWS = in_sizes[0] / D_IN;      // 16384

    uint16_t* xq = (uint16_t*)d_ws;                     // 128 MB
    uint16_t* wq = xq + (size_t)NROWS * D_IN;           //  32 MB

    int nblkx = NROWS * (D_IN / 32);
    int nblkw = D_OUT * (D_IN / 32);
    mx_quant_bf16<<<dim3((nblkx + 255) / 256), dim3(256), 0, stream>>>(x, xq, nblkx);
    mx_quant_bf16<<<dim3((nblkw + 255) / 256), dim3(256), 0, stream>>>(wgt, wq, nblkw);

    dim3 grid(D_OUT / BN, NROWS / BM);   // (16, 64) = 1024 blocks
    gemm_ck_bf16<<<grid, dim3(512), 0, stream>>>(xq, wq, bias, out,
                                                 NROWS, D_IN, D_OUT);
}